// Round 1
// baseline (167.958 us; speedup 1.0000x reference)
//
#include <hip/hip_runtime.h>

// Problem constants (reference: B=16384, DIM_X=2048, K=128)
#define BB 16384
#define DD 2048
#define KK 128
#define NT 64            // DD / 32 k-steps
#define DELTA 1e-3f      // argmax gap below which we re-resolve in fp64

typedef __attribute__((ext_vector_type(8))) short  bf16x8;
typedef __attribute__((ext_vector_type(4))) float  f32x4;
typedef __attribute__((ext_vector_type(4))) unsigned int u32x4;

union V16 { u32x4 u; f32x4 f; bf16x8 s; };

__device__ __forceinline__ void gld16(const void* g, void* l) {
  __builtin_amdgcn_global_load_lds(
      (const __attribute__((address_space(1))) void*)g,
      (__attribute__((address_space(3))) void*)l, 16, 0, 0);
}

// ---------------------------------------------------------------------------
// Prep: split enc_W and dec_W into bf16 hi/lo, laid out in exact MFMA
// B-fragment order: element ((t*8+ct)*64+l)*8+j  <->  W[ct*16+(l&15)][t*32+(l>>4)*8+j]
// Also zeroes the loss/accuracy accumulators and the flag counter.
// ---------------------------------------------------------------------------
__global__ __launch_bounds__(256) void prep_kernel(
    const float* __restrict__ encW, const float* __restrict__ decW,
    unsigned short* __restrict__ wEh, unsigned short* __restrict__ wEl,
    unsigned short* __restrict__ wDh, unsigned short* __restrict__ wDl,
    float* __restrict__ out, unsigned int* __restrict__ counter)
{
  int id = blockIdx.x * 256 + threadIdx.x;           // 0 .. 65535
  if (id == 0) { *counter = 0u; out[2*BB] = 0.f; out[2*BB+1] = 0.f; }
  int sel = id >> 15;                                // 0 = enc, 1 = dec
  int idx = id & 32767;
  int l  = idx & 63;
  int ct = (idx >> 6) & 7;
  int t  = idx >> 9;
  const float* W = sel ? decW : encW;
  unsigned short* oh = sel ? wDh : wEh;
  unsigned short* ol = sel ? wDl : wEl;
  int col = ct * 16 + (l & 15);
  int k0  = t * 32 + ((l >> 4) << 3);
  const float* src = W + (size_t)col * DD + k0;
  V16 vh, vl;
#pragma unroll
  for (int p = 0; p < 4; ++p) {
    unsigned hu[2], lu[2];
#pragma unroll
    for (int q = 0; q < 2; ++q) {
      float f = src[p*2 + q];
      unsigned u  = __float_as_uint(f);
      unsigned rh = u + 0x7FFFu + ((u >> 16) & 1u);   // RNE to bf16
      unsigned hb = rh >> 16;
      float hf = __uint_as_float(hb << 16);
      float r  = f - hf;                               // exact residual
      unsigned ur = __float_as_uint(r);
      unsigned rl = ur + 0x7FFFu + ((ur >> 16) & 1u);
      hu[q] = hb & 0xFFFFu; lu[q] = (rl >> 16) & 0xFFFFu;
    }
    vh.u[p] = (hu[1] << 16) | hu[0];
    vl.u[p] = (lu[1] << 16) | lu[0];
  }
  *(u32x4*)(oh + (size_t)idx * 8) = vh.u;
  *(u32x4*)(ol + (size_t)idx * 8) = vl.u;
}

// ---------------------------------------------------------------------------
// Main fused kernel: 256 blocks x 512 threads. Block = 64 rows.
// Wave w: wr=w>>1 (16-row group), wc=w&1 (64-col half). Two GEMMs (enc, dec)
// accumulated simultaneously; x staged once through LDS (XOR-swizzled source).
// ---------------------------------------------------------------------------
__global__ __launch_bounds__(512) void main_kernel(
    const float* __restrict__ x, const float* __restrict__ y,
    const float* __restrict__ encb, const float* __restrict__ decb,
    const unsigned short* __restrict__ wEh, const unsigned short* __restrict__ wEl,
    const unsigned short* __restrict__ wDh, const unsigned short* __restrict__ wDl,
    float* __restrict__ out, unsigned int* __restrict__ counter,
    unsigned int* __restrict__ list)
{
  __shared__ __align__(16) unsigned char pool[83456];
  const int tid = threadIdx.x;
  const int w  = tid >> 6;
  const int l  = tid & 63;
  const int wr = w >> 1;
  const int wc = w & 1;
  const int rbase = blockIdx.x * 64;

  // staging sources: x chunk (8KB/kstep, swizzled global src) + 4 W frag streams
  const int srow = tid >> 3, sq = tid & 7;
  const float* gX = x + (size_t)(rbase + srow) * DD + ((sq ^ (srow & 7)) << 2);
  const unsigned short* gEh = wEh + (size_t)tid * 8;
  const unsigned short* gEl = wEl + (size_t)tid * 8;
  const unsigned short* gDh = wDh + (size_t)tid * 8;
  const unsigned short* gDl = wDl + (size_t)tid * 8;
  const int wbase = w << 10;                  // wave-uniform LDS byte base

  f32x4 accE[4], accD[4];
  const f32x4 zero4 = {0.f, 0.f, 0.f, 0.f};
#pragma unroll
  for (int c = 0; c < 4; ++c) { accE[c] = zero4; accD[c] = zero4; }

  auto STAGE = [&](int buf, int t) {
    unsigned char* bp = pool + buf * 40960;
    gld16(gX + t * 32,            bp          + wbase);
    gld16(gEh + (size_t)t * 4096, bp + 8192   + wbase);
    gld16(gEl + (size_t)t * 4096, bp + 16384  + wbase);
    gld16(gDh + (size_t)t * 4096, bp + 24576  + wbase);
    gld16(gDl + (size_t)t * 4096, bp + 32768  + wbase);
  };

  STAGE(0, 0);
  __syncthreads();

  const int arow  = wr * 16 + (l & 15);
  const int kq    = (l >> 4) << 1;                              // 16B-block idx
  const int aoff0 = arow * 32 + (( kq      ^ (arow & 7)) << 2); // float idx
  const int aoff1 = arow * 32 + (((kq + 1) ^ (arow & 7)) << 2);
  const int foff  = l * 8;                                      // ushort idx

#pragma unroll 2
  for (int t = 0; t < NT; ++t) {
    const int buf = t & 1;
    if (t + 1 < NT) STAGE(buf ^ 1, t + 1);
    unsigned char* bp = pool + buf * 40960;
    const float* sXf = (const float*)bp;
    f32x4 a0 = *(const f32x4*)(sXf + aoff0);
    f32x4 a1 = *(const f32x4*)(sXf + aoff1);

    // truncation split: x = hi + lo (+ ~2^-16 dropped; covered by DELTA flag)
    V16 vh, vl;
    float fa[8] = {a0[0],a0[1],a0[2],a0[3],a1[0],a1[1],a1[2],a1[3]};
#pragma unroll
    for (int p = 0; p < 4; ++p) {
      unsigned u0 = __float_as_uint(fa[2*p]);
      unsigned u1 = __float_as_uint(fa[2*p+1]);
      vh.u[p] = (u0 >> 16) | (u1 & 0xFFFF0000u);
      float r0 = fa[2*p]   - __uint_as_float(u0 & 0xFFFF0000u);
      float r1 = fa[2*p+1] - __uint_as_float(u1 & 0xFFFF0000u);
      vl.u[p] = (__float_as_uint(r0) >> 16) | (__float_as_uint(r1) & 0xFFFF0000u);
    }
    bf16x8 ah = vh.s, al = vl.s;

    const unsigned short* sEhp = (const unsigned short*)(bp + 8192);
    const unsigned short* sElp = (const unsigned short*)(bp + 16384);
    const unsigned short* sDhp = (const unsigned short*)(bp + 24576);
    const unsigned short* sDlp = (const unsigned short*)(bp + 32768);
#pragma unroll
    for (int c = 0; c < 4; ++c) {
      const int ct = (wc * 4 + c) * 512;
      bf16x8 beh = *(const bf16x8*)(sEhp + ct + foff);
      bf16x8 bel = *(const bf16x8*)(sElp + ct + foff);
      bf16x8 bdh = *(const bf16x8*)(sDhp + ct + foff);
      bf16x8 bdl = *(const bf16x8*)(sDlp + ct + foff);
      accE[c] = __builtin_amdgcn_mfma_f32_16x16x32_bf16(ah, beh, accE[c], 0, 0, 0);
      accE[c] = __builtin_amdgcn_mfma_f32_16x16x32_bf16(al, beh, accE[c], 0, 0, 0);
      accE[c] = __builtin_amdgcn_mfma_f32_16x16x32_bf16(ah, bel, accE[c], 0, 0, 0);
      accE[c] = __builtin_amdgcn_mfma_f32_16x16x32_bf16(al, bel, accE[c], 0, 0, 0);
      accD[c] = __builtin_amdgcn_mfma_f32_16x16x32_bf16(ah, bdh, accD[c], 0, 0, 0);
      accD[c] = __builtin_amdgcn_mfma_f32_16x16x32_bf16(al, bdh, accD[c], 0, 0, 0);
      accD[c] = __builtin_amdgcn_mfma_f32_16x16x32_bf16(ah, bdl, accD[c], 0, 0, 0);
      accD[c] = __builtin_amdgcn_mfma_f32_16x16x32_bf16(al, bdl, accD[c], 0, 0, 0);
    }
    __syncthreads();
  }

  // ---------------- epilogue (overlays the staging pool) ----------------
  float* sT  = (float*)pool;                  // [64][132] dec-GEMM results
  float* sm1 = (float*)(pool + 81920);        // [64][2] top-1
  float* sm2 = (float*)(pool + 82432);        // [64][2] top-2
  int*   si1 = (int*)  (pool + 82944);        // [64][2] argmax

  {
    const int rloc = wr * 16 + ((l >> 4) << 2);
#pragma unroll
    for (int c = 0; c < 4; ++c) {
      const int col = wc * 64 + c * 16 + (l & 15);
#pragma unroll
      for (int i = 0; i < 4; ++i)
        sT[(rloc + i) * 132 + col] = accD[c][i];
    }
    float m1[4], m2[4]; int i1[4];
#pragma unroll
    for (int i = 0; i < 4; ++i) { m1[i] = -3.4e38f; m2[i] = -3.4e38f; i1[i] = 0; }
#pragma unroll
    for (int c = 0; c < 4; ++c) {
      const int col = wc * 64 + c * 16 + (l & 15);
      const float bias = encb[col];
#pragma unroll
      for (int i = 0; i < 4; ++i) {
        float v = accE[c][i] + bias;
        if (v > m1[i]) { m2[i] = m1[i]; m1[i] = v; i1[i] = col; }
        else if (v > m2[i]) { m2[i] = v; }
      }
    }
#pragma unroll
    for (int d = 1; d < 16; d <<= 1) {
#pragma unroll
      for (int i = 0; i < 4; ++i) {
        float om1 = __shfl_xor(m1[i], d);
        float om2 = __shfl_xor(m2[i], d);
        int   oi  = __shfl_xor(i1[i], d);
        if (om1 > m1[i] || (om1 == m1[i] && oi < i1[i])) {
          m2[i] = fmaxf(m1[i], om2); m1[i] = om1; i1[i] = oi;
        } else {
          m2[i] = fmaxf(m2[i], om1);
        }
      }
    }
    if ((l & 15) == 0) {
#pragma unroll
      for (int i = 0; i < 4; ++i) {
        const int rr = rloc + i;
        sm1[rr * 2 + wc] = m1[i];
        sm2[rr * 2 + wc] = m2[i];
        si1[rr * 2 + wc] = i1[i];
      }
    }
  }
  __syncthreads();

  float lossAcc = 0.f, accAcc = 0.f;
  if (l < 8) {
    const int rl = w * 8 + l;
    const int R  = rbase + rl;
    float a1v = sm1[rl*2],   a2v = sm2[rl*2];   int ai = si1[rl*2];
    float b1v = sm1[rl*2+1], b2v = sm2[rl*2+1]; int bi = si1[rl*2+1];
    int kstar; float g1, g2;
    if (b1v > a1v) { kstar = bi; g1 = b1v; g2 = fmaxf(a1v, b2v); }
    else           { kstar = ai; g1 = a1v; g2 = fmaxf(a2v, b1v); }  // tie: lower col
    float yh = sT[rl * 132 + kstar] + decb[kstar];
    out[R]      = yh;
    out[BB + R] = (float)kstar;
    if (g1 - g2 < DELTA) {                       // near-tie: fp64 re-resolve later
      unsigned p = atomicAdd(counter, 1u);
      list[p] = (unsigned)R;
    }
    float yv = y[R];
    float d  = yh - yv;
    lossAcc = d * d;
    float sg = (yh > 0.f) ? 1.f : ((yh < 0.f) ? -1.f : 0.f);
    accAcc = (sg == yv) ? 1.f : 0.f;
  }
#pragma unroll
  for (int d = 1; d < 8; d <<= 1) {
    lossAcc += __shfl_xor(lossAcc, d);
    accAcc  += __shfl_xor(accAcc, d);
  }
  if (l == 0) {
    atomicAdd(&out[2*BB],     lossAcc * (1.f / BB));
    atomicAdd(&out[2*BB + 1], accAcc  * (1.f / BB));
  }
}

// ---------------------------------------------------------------------------
// Fixup: fp64 re-resolution of flagged near-tie rows; patches y_hat, z_hat,
// and the loss/accuracy atomics.
// ---------------------------------------------------------------------------
__global__ __launch_bounds__(256) void fixup_kernel(
    const float* __restrict__ x, const float* __restrict__ y,
    const float* __restrict__ encW, const float* __restrict__ encb,
    const float* __restrict__ decW, const float* __restrict__ decb,
    float* __restrict__ out,
    const unsigned int* __restrict__ counter, const unsigned int* __restrict__ list)
{
  __shared__ double sp[256];
  __shared__ double sc[128];
  __shared__ int ksh;
  const int n = (int)*counter;
  const int tid = threadIdx.x;
  for (int e = blockIdx.x; e < n; e += gridDim.x) {
    const int R = (int)list[e];
    const float* xr = x + (size_t)R * DD;
    {
      const int col = tid & 127, seg = tid >> 7;
      const float* wrow = encW + (size_t)col * DD + seg * 1024;
      const float* xs = xr + seg * 1024;
      double s = 0.0;
      for (int k = 0; k < 1024; ++k) s = fma((double)xs[k], (double)wrow[k], s);
      sp[tid] = s;
    }
    __syncthreads();
    if (tid < 128) sc[tid] = sp[tid] + sp[tid + 128] + (double)encb[tid];
    __syncthreads();
    if (tid == 0) {
      double best = sc[0]; int bi = 0;
      for (int c = 1; c < 128; ++c) if (sc[c] > best) { best = sc[c]; bi = c; }
      ksh = bi;
    }
    __syncthreads();
    const int kstar = ksh;
    {
      const float* dr = decW + (size_t)kstar * DD;
      const int k0 = tid * 8;
      double s = 0.0;
#pragma unroll
      for (int j = 0; j < 8; ++j) s = fma((double)xr[k0 + j], (double)dr[k0 + j], s);
      sp[tid] = s;
    }
    __syncthreads();
    for (int st = 128; st > 0; st >>= 1) {
      if (tid < st) sp[tid] += sp[tid + st];
      __syncthreads();
    }
    if (tid == 0) {
      float yh = (float)(sp[0] + (double)decb[kstar]);
      float yv = y[R];
      float old = out[R];
      float dn = yh - yv, dol = old - yv;
      atomicAdd(&out[2*BB], (dn*dn - dol*dol) * (1.f / BB));
      float sgn = (yh  > 0.f) ? 1.f : ((yh  < 0.f) ? -1.f : 0.f);
      float sgo = (old > 0.f) ? 1.f : ((old < 0.f) ? -1.f : 0.f);
      float mn = (sgn == yv) ? 1.f : 0.f;
      float mo = (sgo == yv) ? 1.f : 0.f;
      atomicAdd(&out[2*BB + 1], (mn - mo) * (1.f / BB));
      out[R]      = yh;
      out[BB + R] = (float)kstar;
    }
    __syncthreads();
  }
}

extern "C" void kernel_launch(void* const* d_in, const int* in_sizes, int n_in,
                              void* d_out, int out_size, void* d_ws, size_t ws_size,
                              hipStream_t stream)
{
  const float* x    = (const float*)d_in[0];
  const float* y    = (const float*)d_in[1];
  // d_in[2] = z (unused by the reference computation)
  const float* encW = (const float*)d_in[3];
  const float* encb = (const float*)d_in[4];
  const float* decW = (const float*)d_in[5];   // [1,128,2048] -> row-major [128][2048]
  const float* decb = (const float*)d_in[6];
  float* out = (float*)d_out;

  unsigned char* ws = (unsigned char*)d_ws;
  unsigned short* wEh = (unsigned short*)ws;
  unsigned short* wEl = (unsigned short*)(ws + 524288);
  unsigned short* wDh = (unsigned short*)(ws + 1048576);
  unsigned short* wDl = (unsigned short*)(ws + 1572864);
  unsigned int* counter = (unsigned int*)(ws + 2097152);
  unsigned int* list    = (unsigned int*)(ws + 2097152 + 16);

  prep_kernel<<<256, 256, 0, stream>>>(encW, decW, wEh, wEl, wDh, wDl, out, counter);
  main_kernel<<<256, 512, 0, stream>>>(x, y, encb, decb, wEh, wEl, wDh, wDl,
                                       out, counter, list);
  fixup_kernel<<<256, 256, 0, stream>>>(x, y, encW, encb, decW, decb,
                                        out, counter, list);
}

// Round 2
// 126.265 us; speedup vs baseline: 1.3302x; 1.3302x over previous
//
#include <hip/hip_runtime.h>

// Problem constants (reference: B=16384, DIM_X=2048, K=128)
#define BB 16384
#define DD 2048
#define KK 128
#define NT 64            // DD / 32 k-steps
#define RPB 32           // rows per block
#define NBLK 512         // blocks (2 per CU)
#define DELTA 1e-3f      // argmax gap below which we re-resolve in fp64

typedef __attribute__((ext_vector_type(8))) short  bf16x8;
typedef __attribute__((ext_vector_type(4))) float  f32x4;
typedef __attribute__((ext_vector_type(4))) unsigned int u32x4;

union V16 { u32x4 u; f32x4 f; bf16x8 s; };

__device__ __forceinline__ void gld16(const void* g, void* l) {
  __builtin_amdgcn_global_load_lds(
      (const __attribute__((address_space(1))) void*)g,
      (__attribute__((address_space(3))) void*)l, 16, 0, 0);
}

// ---------------------------------------------------------------------------
// Prep: split enc_W into bf16 hi/lo and dec_W into bf16 hi, laid out in MFMA
// B-fragment order: element ((t*8+ct)*64+l)*8+j  <->  W[ct*16+(l&15)][t*32+(l>>4)*8+j]
// Also zeroes the loss/accuracy accumulators and the flag counter.
// ---------------------------------------------------------------------------
__global__ __launch_bounds__(256) void prep_kernel(
    const float* __restrict__ encW, const float* __restrict__ decW,
    unsigned short* __restrict__ wEh, unsigned short* __restrict__ wEl,
    unsigned short* __restrict__ wDh,
    float* __restrict__ out, unsigned int* __restrict__ counter)
{
  int id = blockIdx.x * 256 + threadIdx.x;           // 0 .. 65535
  if (id == 0) { *counter = 0u; out[2*BB] = 0.f; out[2*BB+1] = 0.f; }
  int sel = id >> 15;                                // 0 = enc, 1 = dec
  int idx = id & 32767;
  int l  = idx & 63;
  int ct = (idx >> 6) & 7;
  int t  = idx >> 9;
  const float* W = sel ? decW : encW;
  int col = ct * 16 + (l & 15);
  int k0  = t * 32 + ((l >> 4) << 3);
  const float* src = W + (size_t)col * DD + k0;
  V16 vh, vl;
#pragma unroll
  for (int p = 0; p < 4; ++p) {
    unsigned hu[2], lu[2];
#pragma unroll
    for (int q = 0; q < 2; ++q) {
      float f = src[p*2 + q];
      unsigned u  = __float_as_uint(f);
      unsigned rh = u + 0x7FFFu + ((u >> 16) & 1u);   // RNE to bf16
      unsigned hb = rh >> 16;
      float hf = __uint_as_float(hb << 16);
      float r  = f - hf;                               // exact residual
      unsigned ur = __float_as_uint(r);
      unsigned rl = ur + 0x7FFFu + ((ur >> 16) & 1u);
      hu[q] = hb & 0xFFFFu; lu[q] = (rl >> 16) & 0xFFFFu;
    }
    vh.u[p] = (hu[1] << 16) | hu[0];
    vl.u[p] = (lu[1] << 16) | lu[0];
  }
  if (sel == 0) {
    *(u32x4*)(wEh + (size_t)idx * 8) = vh.u;
    *(u32x4*)(wEl + (size_t)idx * 8) = vl.u;
  } else {
    *(u32x4*)(wDh + (size_t)idx * 8) = vh.u;
  }
}

// ---------------------------------------------------------------------------
// Main fused kernel: 512 blocks x 512 threads (2 blocks/CU). Block = 32 rows.
// Wave w in 0..7 owns col-tile w (16 cols) of BOTH GEMMs, all 32 rows (m=2).
// x staged through 4KB double-buffered LDS (swizzled source); W fragments
// loaded straight global->VGPR (L2-resident, no LDS amplification).
// ---------------------------------------------------------------------------
__global__ __launch_bounds__(512, 4) void main_kernel(
    const float* __restrict__ x, const float* __restrict__ y,
    const float* __restrict__ encb, const float* __restrict__ decb,
    const unsigned short* __restrict__ wEh, const unsigned short* __restrict__ wEl,
    const unsigned short* __restrict__ wDh,
    float* __restrict__ out, unsigned int* __restrict__ counter,
    unsigned int* __restrict__ list)
{
  __shared__ __align__(16) unsigned char pool[19968];
  const int tid = threadIdx.x;
  const int w = tid >> 6, l = tid & 63;
  const int rbase = blockIdx.x * RPB;

  // x staging: threads 0..255 stage 32 rows x 32 floats (4KB), swizzled source
  const int srow = tid >> 3, sq = tid & 7;
  const float* gX = x + (size_t)(rbase + srow) * DD + ((sq ^ (srow & 7)) << 2);
  const int wbase = w << 10;                // wave-uniform LDS byte base (w<4)

  // B fragment sources (direct to regs), col-tile = w
  const size_t boff = ((size_t)w * 64 + l) * 8;
  const unsigned short* gEh = wEh + boff;
  const unsigned short* gEl = wEl + boff;
  const unsigned short* gDh = wDh + boff;

  f32x4 accE[2], accD[2];
  const f32x4 zero4 = {0.f, 0.f, 0.f, 0.f};
#pragma unroll
  for (int rt = 0; rt < 2; ++rt) { accE[rt] = zero4; accD[rt] = zero4; }

  // A-fragment LDS offsets (float index), chunk-swizzled
  int aoff[2][2];
#pragma unroll
  for (int rt = 0; rt < 2; ++rt) {
    int row = rt * 16 + (l & 15);
    int c0  = (l >> 4) << 1;
    aoff[rt][0] = row * 32 + (((c0    ) ^ (row & 7)) << 2);
    aoff[rt][1] = row * 32 + (((c0 + 1) ^ (row & 7)) << 2);
  }

  auto STAGE = [&](int buf, int t) {
    if (tid < 256) gld16(gX + (size_t)t * 32, pool + buf * 4096 + wbase);
  };
  auto LDB = [&](const unsigned short* base, int t) -> bf16x8 {
    return *(const bf16x8*)(base + (size_t)t * 4096);
  };
  auto COMPUTE = [&](int buf, bf16x8 bEh, bf16x8 bEl, bf16x8 bDh) {
    const float* sXf = (const float*)(pool + buf * 4096);
#pragma unroll
    for (int rt = 0; rt < 2; ++rt) {
      f32x4 a0 = *(const f32x4*)(sXf + aoff[rt][0]);
      f32x4 a1 = *(const f32x4*)(sXf + aoff[rt][1]);
      V16 vh, vl;
      float fa[8] = {a0[0],a0[1],a0[2],a0[3],a1[0],a1[1],a1[2],a1[3]};
#pragma unroll
      for (int p = 0; p < 4; ++p) {
        unsigned u0 = __float_as_uint(fa[2*p]);
        unsigned u1 = __float_as_uint(fa[2*p+1]);
        vh.u[p] = (u0 >> 16) | (u1 & 0xFFFF0000u);
        float r0 = fa[2*p]   - __uint_as_float(u0 & 0xFFFF0000u);
        float r1 = fa[2*p+1] - __uint_as_float(u1 & 0xFFFF0000u);
        vl.u[p] = (__float_as_uint(r0) >> 16) | (__float_as_uint(r1) & 0xFFFF0000u);
      }
      bf16x8 ah = vh.s, al = vl.s;
      accE[rt] = __builtin_amdgcn_mfma_f32_16x16x32_bf16(ah, bEh, accE[rt], 0, 0, 0);
      accE[rt] = __builtin_amdgcn_mfma_f32_16x16x32_bf16(al, bEh, accE[rt], 0, 0, 0);
      accE[rt] = __builtin_amdgcn_mfma_f32_16x16x32_bf16(ah, bEl, accE[rt], 0, 0, 0);
      accD[rt] = __builtin_amdgcn_mfma_f32_16x16x32_bf16(ah, bDh, accD[rt], 0, 0, 0);
      accD[rt] = __builtin_amdgcn_mfma_f32_16x16x32_bf16(al, bDh, accD[rt], 0, 0, 0);
    }
  };

  bf16x8 bEh0 = LDB(gEh, 0), bEl0 = LDB(gEl, 0), bDh0 = LDB(gDh, 0);
  STAGE(0, 0);
  __syncthreads();

  bf16x8 bEh1, bEl1, bDh1;
  for (int t = 0; t < NT; t += 2) {
    // phase A: compute t (buf0/set0), prefetch t+1 (buf1/set1)
    STAGE(1, t + 1);
    bEh1 = LDB(gEh, t + 1); bEl1 = LDB(gEl, t + 1); bDh1 = LDB(gDh, t + 1);
    COMPUTE(0, bEh0, bEl0, bDh0);
    __syncthreads();
    // phase B: compute t+1 (buf1/set1), prefetch t+2 (buf0/set0)
    if (t + 2 < NT) {
      STAGE(0, t + 2);
      bEh0 = LDB(gEh, t + 2); bEl0 = LDB(gEl, t + 2); bDh0 = LDB(gDh, t + 2);
    }
    COMPUTE(1, bEh1, bEl1, bDh1);
    __syncthreads();
  }

  // ---------------- epilogue (overlays the staging pool) ----------------
  float* sT  = (float*)pool;                  // [32][132] dec-GEMM results
  float* sm1 = (float*)(pool + 16896);        // [32][8] top-1
  float* sm2 = (float*)(pool + 17920);        // [32][8] top-2
  int*   si1 = (int*)  (pool + 18944);        // [32][8] argmax col

  {
    const int q = l >> 4, c = l & 15;
    const int col = w * 16 + c;
#pragma unroll
    for (int rt = 0; rt < 2; ++rt)
#pragma unroll
      for (int i = 0; i < 4; ++i)
        sT[(rt * 16 + q * 4 + i) * 132 + col] = accD[rt][i];

    const float bias = encb[col];
    float m1v[8], m2v[8]; int i1v[8];
#pragma unroll
    for (int rt = 0; rt < 2; ++rt)
#pragma unroll
      for (int i = 0; i < 4; ++i) {
        int j = rt * 4 + i;
        m1v[j] = accE[rt][i] + bias;
        m2v[j] = -3.4e38f;
        i1v[j] = col;
      }
#pragma unroll
    for (int d = 1; d < 16; d <<= 1) {
#pragma unroll
      for (int j = 0; j < 8; ++j) {
        float om1 = __shfl_xor(m1v[j], d);
        float om2 = __shfl_xor(m2v[j], d);
        int   oi  = __shfl_xor(i1v[j], d);
        if (om1 > m1v[j] || (om1 == m1v[j] && oi < i1v[j])) {
          m2v[j] = fmaxf(m1v[j], om2); m1v[j] = om1; i1v[j] = oi;
        } else {
          m2v[j] = fmaxf(m2v[j], om1);
        }
      }
    }
    if (c == 0) {
#pragma unroll
      for (int rt = 0; rt < 2; ++rt)
#pragma unroll
        for (int i = 0; i < 4; ++i) {
          int row = rt * 16 + q * 4 + i;
          int j = rt * 4 + i;
          sm1[row * 8 + w] = m1v[j];
          sm2[row * 8 + w] = m2v[j];
          si1[row * 8 + w] = i1v[j];
        }
    }
  }
  __syncthreads();

  float lossAcc = 0.f, accAcc = 0.f;
  if (tid < RPB) {
    const int row = tid, R = rbase + row;
    float m1 = -3.4e38f, m2 = -3.4e38f; int i1 = 0;
#pragma unroll
    for (int cdx = 0; cdx < 8; ++cdx) {
      float a1 = sm1[row * 8 + cdx], a2 = sm2[row * 8 + cdx];
      int ai = si1[row * 8 + cdx];
      if (a1 > m1) { m2 = fmaxf(m1, a2); m1 = a1; i1 = ai; }
      else         { m2 = fmaxf(m2, a1); }
    }
    float yh = sT[row * 132 + i1] + decb[i1];
    out[R]      = yh;
    out[BB + R] = (float)i1;
    if (m1 - m2 < DELTA) {                     // near-tie: fp64 re-resolve later
      unsigned p = atomicAdd(counter, 1u);
      list[p] = (unsigned)R;
    }
    float yv = y[R];
    float d  = yh - yv;
    lossAcc = d * d;
    float sg = (yh > 0.f) ? 1.f : ((yh < 0.f) ? -1.f : 0.f);
    accAcc = (sg == yv) ? 1.f : 0.f;
  }
#pragma unroll
  for (int d = 1; d < 64; d <<= 1) {
    lossAcc += __shfl_xor(lossAcc, d);
    accAcc  += __shfl_xor(accAcc, d);
  }
  if (tid == 0) {
    atomicAdd(&out[2*BB],     lossAcc * (1.f / BB));
    atomicAdd(&out[2*BB + 1], accAcc  * (1.f / BB));
  }
}

// ---------------------------------------------------------------------------
// Fixup: fp64 re-resolution of flagged near-tie rows; patches y_hat, z_hat,
// and the loss/accuracy atomics.
// ---------------------------------------------------------------------------
__global__ __launch_bounds__(256) void fixup_kernel(
    const float* __restrict__ x, const float* __restrict__ y,
    const float* __restrict__ encW, const float* __restrict__ encb,
    const float* __restrict__ decW, const float* __restrict__ decb,
    float* __restrict__ out,
    const unsigned int* __restrict__ counter, const unsigned int* __restrict__ list)
{
  __shared__ double sp[256];
  __shared__ double sc[128];
  __shared__ int ksh;
  const int n = (int)*counter;
  const int tid = threadIdx.x;
  for (int e = blockIdx.x; e < n; e += gridDim.x) {
    const int R = (int)list[e];
    const float* xr = x + (size_t)R * DD;
    {
      const int col = tid & 127, seg = tid >> 7;
      const float* wrow = encW + (size_t)col * DD + seg * 1024;
      const float* xs = xr + seg * 1024;
      double s = 0.0;
      for (int k = 0; k < 1024; ++k) s = fma((double)xs[k], (double)wrow[k], s);
      sp[tid] = s;
    }
    __syncthreads();
    if (tid < 128) sc[tid] = sp[tid] + sp[tid + 128] + (double)encb[tid];
    __syncthreads();
    if (tid == 0) {
      double best = sc[0]; int bi = 0;
      for (int c = 1; c < 128; ++c) if (sc[c] > best) { best = sc[c]; bi = c; }
      ksh = bi;
    }
    __syncthreads();
    const int kstar = ksh;
    {
      const float* dr = decW + (size_t)kstar * DD;
      const int k0 = tid * 8;
      double s = 0.0;
#pragma unroll
      for (int j = 0; j < 8; ++j) s = fma((double)xr[k0 + j], (double)dr[k0 + j], s);
      sp[tid] = s;
    }
    __syncthreads();
    for (int st = 128; st > 0; st >>= 1) {
      if (tid < st) sp[tid] += sp[tid + st];
      __syncthreads();
    }
    if (tid == 0) {
      float yh = (float)(sp[0] + (double)decb[kstar]);
      float yv = y[R];
      float old = out[R];
      float dn = yh - yv, dol = old - yv;
      atomicAdd(&out[2*BB], (dn*dn - dol*dol) * (1.f / BB));
      float sgn = (yh  > 0.f) ? 1.f : ((yh  < 0.f) ? -1.f : 0.f);
      float sgo = (old > 0.f) ? 1.f : ((old < 0.f) ? -1.f : 0.f);
      float mn = (sgn == yv) ? 1.f : 0.f;
      float mo = (sgo == yv) ? 1.f : 0.f;
      atomicAdd(&out[2*BB + 1], (mn - mo) * (1.f / BB));
      out[R]      = yh;
      out[BB + R] = (float)kstar;
    }
    __syncthreads();
  }
}

extern "C" void kernel_launch(void* const* d_in, const int* in_sizes, int n_in,
                              void* d_out, int out_size, void* d_ws, size_t ws_size,
                              hipStream_t stream)
{
  const float* x    = (const float*)d_in[0];
  const float* y    = (const float*)d_in[1];
  // d_in[2] = z (unused by the reference computation)
  const float* encW = (const float*)d_in[3];
  const float* encb = (const float*)d_in[4];
  const float* decW = (const float*)d_in[5];   // [1,128,2048] -> row-major [128][2048]
  const float* decb = (const float*)d_in[6];
  float* out = (float*)d_out;

  unsigned char* ws = (unsigned char*)d_ws;
  unsigned short* wEh = (unsigned short*)ws;
  unsigned short* wEl = (unsigned short*)(ws + 524288);
  unsigned short* wDh = (unsigned short*)(ws + 1048576);
  unsigned int* counter = (unsigned int*)(ws + 1572864);
  unsigned int* list    = (unsigned int*)(ws + 1572864 + 16);

  prep_kernel<<<256, 256, 0, stream>>>(encW, decW, wEh, wEl, wDh, out, counter);
  main_kernel<<<NBLK, 512, 0, stream>>>(x, y, encb, decb, wEh, wEl, wDh,
                                        out, counter, list);
  fixup_kernel<<<256, 256, 0, stream>>>(x, y, encW, encb, decW, decb,
                                        out, counter, list);
}

// Round 3
// 107.925 us; speedup vs baseline: 1.5563x; 1.1699x over previous
//
#include <hip/hip_runtime.h>

// Problem constants (reference: B=16384, DIM_X=2048, K=128)
#define BB 16384
#define DD 2048
#define KK 128
#define NT 64            // DD / 32 k-steps
#define RPB 32           // rows per block
#define NBLK 512         // blocks (2 per CU)
#define DELTA 1e-3f      // argmax gap below which we re-resolve in fp64

typedef __attribute__((ext_vector_type(8))) short  bf16x8;
typedef __attribute__((ext_vector_type(4))) float  f32x4;
typedef __attribute__((ext_vector_type(2))) float  f32x2;
typedef __attribute__((ext_vector_type(4))) unsigned int u32x4;

union V16 { u32x4 u; f32x4 f; bf16x8 s; };

// LDS buffer geometry: xh [32 rows][80 B] + xl [32 rows][80 B] per k-step buffer.
// Row stride 80 B = 20 dwords: 16 rows map to 8 disjoint 4-bank spans, 2 rows
// each -> 2-way (free) on ds_read_b128; 16 B aligned.
#define XROWB 80
#define XLOFF 2560       // xl offset within buffer
#define BUFSZ 5120       // bytes per k-step buffer (hi+lo)

// ---------------------------------------------------------------------------
// Prep: split enc_W into bf16 hi/lo and dec_W into bf16 hi, laid out in MFMA
// B-fragment order: element ((t*8+ct)*64+l)*8+j <-> W[ct*16+(l&15)][t*32+(l>>4)*8+j]
// Also zeroes the loss/accuracy accumulators and the flag counter.
// ---------------------------------------------------------------------------
__global__ __launch_bounds__(256) void prep_kernel(
    const float* __restrict__ encW, const float* __restrict__ decW,
    unsigned short* __restrict__ wEh, unsigned short* __restrict__ wEl,
    unsigned short* __restrict__ wDh,
    float* __restrict__ out, unsigned int* __restrict__ counter)
{
  int id = blockIdx.x * 256 + threadIdx.x;           // 0 .. 65535
  if (id == 0) { *counter = 0u; out[2*BB] = 0.f; out[2*BB+1] = 0.f; }
  int sel = id >> 15;                                // 0 = enc, 1 = dec
  int idx = id & 32767;
  int l  = idx & 63;
  int ct = (idx >> 6) & 7;
  int t  = idx >> 9;
  const float* W = sel ? decW : encW;
  int col = ct * 16 + (l & 15);
  int k0  = t * 32 + ((l >> 4) << 3);
  const float* src = W + (size_t)col * DD + k0;
  V16 vh, vl;
#pragma unroll
  for (int p = 0; p < 4; ++p) {
    unsigned hu[2], lu[2];
#pragma unroll
    for (int q = 0; q < 2; ++q) {
      float f = src[p*2 + q];
      unsigned u  = __float_as_uint(f);
      unsigned rh = u + 0x7FFFu + ((u >> 16) & 1u);   // RNE to bf16
      unsigned hb = rh >> 16;
      float hf = __uint_as_float(hb << 16);
      float r  = f - hf;                               // exact residual
      unsigned ur = __float_as_uint(r);
      unsigned rl = ur + 0x7FFFu + ((ur >> 16) & 1u);
      hu[q] = hb & 0xFFFFu; lu[q] = (rl >> 16) & 0xFFFFu;
    }
    vh.u[p] = (hu[1] << 16) | hu[0];
    vl.u[p] = (lu[1] << 16) | lu[0];
  }
  if (sel == 0) {
    *(u32x4*)(wEh + (size_t)idx * 8) = vh.u;
    *(u32x4*)(wEl + (size_t)idx * 8) = vl.u;
  } else {
    *(u32x4*)(wDh + (size_t)idx * 8) = vh.u;
  }
}

// ---------------------------------------------------------------------------
// Main fused kernel: 512 blocks x 512 threads (2 blocks/CU). Block = 32 rows.
// Wave w owns col-tile w (16 cols) of BOTH GEMMs, all 32 rows (rt=2).
// x is split to bf16 hi/lo ONCE at stage time into LDS (conflict-free 80B rows);
// waves ds_read_b128 A-fragments directly. W fragments global->VGPR (L1/L2).
// Per wave/k-step: 4 ds_read_b128 + 8 MFMA (enc: ah*bh+al*bh+ah*bl; dec: ah*bh).
// ---------------------------------------------------------------------------
__global__ __launch_bounds__(512, 4) void main_kernel(
    const float* __restrict__ x, const float* __restrict__ y,
    const float* __restrict__ encb, const float* __restrict__ decb,
    const unsigned short* __restrict__ wEh, const unsigned short* __restrict__ wEl,
    const unsigned short* __restrict__ wDh,
    float* __restrict__ out, unsigned int* __restrict__ counter,
    unsigned int* __restrict__ list)
{
  __shared__ __align__(16) unsigned char pool[19968];
  const int tid = threadIdx.x;
  const int w = tid >> 6, l = tid & 63;
  const int rbase = blockIdx.x * RPB;

  // stage addressing: thread -> (row sr, k-pair kp); 2 consecutive floats
  const int sr = tid >> 4, kp = tid & 15;
  const float* gXp = x + (size_t)(rbase + sr) * DD + kp * 2;
  const int whoff = sr * XROWB + kp * 4;      // byte offset of hi word

  // B fragment sources (direct to regs), col-tile = w
  const size_t boff = ((size_t)w * 64 + l) * 8;
  const unsigned short* gEh = wEh + boff;
  const unsigned short* gEl = wEl + boff;
  const unsigned short* gDh = wDh + boff;

  // A-fragment LDS byte offsets (within a buffer)
  int raoff[2];
#pragma unroll
  for (int rt = 0; rt < 2; ++rt)
    raoff[rt] = (rt * 16 + (l & 15)) * XROWB + (l >> 4) * 16;

  f32x4 accE[2], accD[2];
  const f32x4 zero4 = {0.f, 0.f, 0.f, 0.f};
#pragma unroll
  for (int rt = 0; rt < 2; ++rt) { accE[rt] = zero4; accD[rt] = zero4; }

  auto LDX = [&](int t) -> f32x2 {
    return *(const f32x2*)(gXp + (size_t)t * 32);
  };
  auto WRX = [&](int buf, f32x2 v) {
    unsigned u0 = __float_as_uint(v[0]);
    unsigned u1 = __float_as_uint(v[1]);
    unsigned hi = (u0 >> 16) | (u1 & 0xFFFF0000u);
    float r0 = v[0] - __uint_as_float(u0 & 0xFFFF0000u);
    float r1 = v[1] - __uint_as_float(u1 & 0xFFFF0000u);
    unsigned lo = (__float_as_uint(r0) >> 16) | (__float_as_uint(r1) & 0xFFFF0000u);
    unsigned char* bp = pool + buf * BUFSZ + whoff;
    *(unsigned*)bp            = hi;
    *(unsigned*)(bp + XLOFF)  = lo;
  };
  auto LDB = [&](const unsigned short* base, int t) -> bf16x8 {
    return *(const bf16x8*)(base + (size_t)t * 4096);
  };
  auto COMPUTE = [&](int buf, bf16x8 bEh, bf16x8 bEl, bf16x8 bDh) {
    const unsigned char* bp = pool + buf * BUFSZ;
#pragma unroll
    for (int rt = 0; rt < 2; ++rt) {
      bf16x8 ah = *(const bf16x8*)(bp + raoff[rt]);
      bf16x8 al = *(const bf16x8*)(bp + raoff[rt] + XLOFF);
      accE[rt] = __builtin_amdgcn_mfma_f32_16x16x32_bf16(ah, bEh, accE[rt], 0, 0, 0);
      accE[rt] = __builtin_amdgcn_mfma_f32_16x16x32_bf16(al, bEh, accE[rt], 0, 0, 0);
      accE[rt] = __builtin_amdgcn_mfma_f32_16x16x32_bf16(ah, bEl, accE[rt], 0, 0, 0);
      accD[rt] = __builtin_amdgcn_mfma_f32_16x16x32_bf16(ah, bDh, accD[rt], 0, 0, 0);
    }
  };

  // prologue
  bf16x8 bEh0 = LDB(gEh, 0), bEl0 = LDB(gEl, 0), bDh0 = LDB(gDh, 0);
  WRX(0, LDX(0));
  __syncthreads();

  bf16x8 bEh1, bEl1, bDh1;
  for (int t = 0; t < NT; t += 2) {
    // phase A: compute buf0/set0; prefetch t+1 into buf1/set1
    f32x2 xr1 = LDX(t + 1);
    bEh1 = LDB(gEh, t + 1); bEl1 = LDB(gEl, t + 1); bDh1 = LDB(gDh, t + 1);
    COMPUTE(0, bEh0, bEl0, bDh0);
    WRX(1, xr1);
    __syncthreads();
    // phase B: compute buf1/set1; prefetch t+2 into buf0/set0
    if (t + 2 < NT) {
      f32x2 xr0 = LDX(t + 2);
      bEh0 = LDB(gEh, t + 2); bEl0 = LDB(gEl, t + 2); bDh0 = LDB(gDh, t + 2);
      COMPUTE(1, bEh1, bEl1, bDh1);
      WRX(0, xr0);
    } else {
      COMPUTE(1, bEh1, bEl1, bDh1);
    }
    __syncthreads();
  }

  // ---------------- epilogue (overlays the staging pool) ----------------
  float* sT  = (float*)pool;                  // [32][132] dec-GEMM results
  float* sm1 = (float*)(pool + 16896);        // [32][8] top-1
  float* sm2 = (float*)(pool + 17920);        // [32][8] top-2
  int*   si1 = (int*)  (pool + 18944);        // [32][8] argmax col

  {
    const int q = l >> 4, c = l & 15;
    const int col = w * 16 + c;
#pragma unroll
    for (int rt = 0; rt < 2; ++rt)
#pragma unroll
      for (int i = 0; i < 4; ++i)
        sT[(rt * 16 + q * 4 + i) * 132 + col] = accD[rt][i];

    const float bias = encb[col];
    float m1v[8], m2v[8]; int i1v[8];
#pragma unroll
    for (int rt = 0; rt < 2; ++rt)
#pragma unroll
      for (int i = 0; i < 4; ++i) {
        int j = rt * 4 + i;
        m1v[j] = accE[rt][i] + bias;
        m2v[j] = -3.4e38f;
        i1v[j] = col;
      }
#pragma unroll
    for (int d = 1; d < 16; d <<= 1) {
#pragma unroll
      for (int j = 0; j < 8; ++j) {
        float om1 = __shfl_xor(m1v[j], d);
        float om2 = __shfl_xor(m2v[j], d);
        int   oi  = __shfl_xor(i1v[j], d);
        if (om1 > m1v[j] || (om1 == m1v[j] && oi < i1v[j])) {
          m2v[j] = fmaxf(m1v[j], om2); m1v[j] = om1; i1v[j] = oi;
        } else {
          m2v[j] = fmaxf(m2v[j], om1);
        }
      }
    }
    if (c == 0) {
#pragma unroll
      for (int rt = 0; rt < 2; ++rt)
#pragma unroll
        for (int i = 0; i < 4; ++i) {
          int row = rt * 16 + q * 4 + i;
          int j = rt * 4 + i;
          sm1[row * 8 + w] = m1v[j];
          sm2[row * 8 + w] = m2v[j];
          si1[row * 8 + w] = i1v[j];
        }
    }
  }
  __syncthreads();

  float lossAcc = 0.f, accAcc = 0.f;
  if (tid < RPB) {
    const int row = tid, R = rbase + row;
    float m1 = -3.4e38f, m2 = -3.4e38f; int i1 = 0;
#pragma unroll
    for (int cdx = 0; cdx < 8; ++cdx) {
      float a1 = sm1[row * 8 + cdx], a2 = sm2[row * 8 + cdx];
      int ai = si1[row * 8 + cdx];
      if (a1 > m1) { m2 = fmaxf(m1, a2); m1 = a1; i1 = ai; }
      else         { m2 = fmaxf(m2, a1); }
    }
    float yh = sT[row * 132 + i1] + decb[i1];
    out[R]      = yh;
    out[BB + R] = (float)i1;
    if (m1 - m2 < DELTA) {                     // near-tie: fp64 re-resolve later
      unsigned p = atomicAdd(counter, 1u);
      list[p] = (unsigned)R;
    }
    float yv = y[R];
    float d  = yh - yv;
    lossAcc = d * d;
    float sg = (yh > 0.f) ? 1.f : ((yh < 0.f) ? -1.f : 0.f);
    accAcc = (sg == yv) ? 1.f : 0.f;
  }
#pragma unroll
  for (int d = 1; d < 64; d <<= 1) {
    lossAcc += __shfl_xor(lossAcc, d);
    accAcc  += __shfl_xor(accAcc, d);
  }
  if (tid == 0) {
    atomicAdd(&out[2*BB],     lossAcc * (1.f / BB));
    atomicAdd(&out[2*BB + 1], accAcc  * (1.f / BB));
  }
}

// ---------------------------------------------------------------------------
// Fixup: fp64 re-resolution of flagged near-tie rows; patches y_hat, z_hat,
// and the loss/accuracy atomics.
// ---------------------------------------------------------------------------
__global__ __launch_bounds__(256) void fixup_kernel(
    const float* __restrict__ x, const float* __restrict__ y,
    const float* __restrict__ encW, const float* __restrict__ encb,
    const float* __restrict__ decW, const float* __restrict__ decb,
    float* __restrict__ out,
    const unsigned int* __restrict__ counter, const unsigned int* __restrict__ list)
{
  __shared__ double sp[256];
  __shared__ double sc[128];
  __shared__ int ksh;
  const int n = (int)*counter;
  const int tid = threadIdx.x;
  for (int e = blockIdx.x; e < n; e += gridDim.x) {
    const int R = (int)list[e];
    const float* xr = x + (size_t)R * DD;
    {
      const int col = tid & 127, seg = tid >> 7;
      const float* wrow = encW + (size_t)col * DD + seg * 1024;
      const float* xs = xr + seg * 1024;
      double s = 0.0;
      for (int k = 0; k < 1024; ++k) s = fma((double)xs[k], (double)wrow[k], s);
      sp[tid] = s;
    }
    __syncthreads();
    if (tid < 128) sc[tid] = sp[tid] + sp[tid + 128] + (double)encb[tid];
    __syncthreads();
    if (tid == 0) {
      double best = sc[0]; int bi = 0;
      for (int c = 1; c < 128; ++c) if (sc[c] > best) { best = sc[c]; bi = c; }
      ksh = bi;
    }
    __syncthreads();
    const int kstar = ksh;
    {
      const float* dr = decW + (size_t)kstar * DD;
      const int k0 = tid * 8;
      double s = 0.0;
#pragma unroll
      for (int j = 0; j < 8; ++j) s = fma((double)xr[k0 + j], (double)dr[k0 + j], s);
      sp[tid] = s;
    }
    __syncthreads();
    for (int st = 128; st > 0; st >>= 1) {
      if (tid < st) sp[tid] += sp[tid + st];
      __syncthreads();
    }
    if (tid == 0) {
      float yh = (float)(sp[0] + (double)decb[kstar]);
      float yv = y[R];
      float old = out[R];
      float dn = yh - yv, dol = old - yv;
      atomicAdd(&out[2*BB], (dn*dn - dol*dol) * (1.f / BB));
      float sgn = (yh  > 0.f) ? 1.f : ((yh  < 0.f) ? -1.f : 0.f);
      float sgo = (old > 0.f) ? 1.f : ((old < 0.f) ? -1.f : 0.f);
      float mn = (sgn == yv) ? 1.f : 0.f;
      float mo = (sgo == yv) ? 1.f : 0.f;
      atomicAdd(&out[2*BB + 1], (mn - mo) * (1.f / BB));
      out[R]      = yh;
      out[BB + R] = (float)kstar;
    }
    __syncthreads();
  }
}

extern "C" void kernel_launch(void* const* d_in, const int* in_sizes, int n_in,
                              void* d_out, int out_size, void* d_ws, size_t ws_size,
                              hipStream_t stream)
{
  const float* x    = (const float*)d_in[0];
  const float* y    = (const float*)d_in[1];
  // d_in[2] = z (unused by the reference computation)
  const float* encW = (const float*)d_in[3];
  const float* encb = (const float*)d_in[4];
  const float* decW = (const float*)d_in[5];   // [1,128,2048] -> row-major [128][2048]
  const float* decb = (const float*)d_in[6];
  float* out = (float*)d_out;

  unsigned char* ws = (unsigned char*)d_ws;
  unsigned short* wEh = (unsigned short*)ws;
  unsigned short* wEl = (unsigned short*)(ws + 524288);
  unsigned short* wDh = (unsigned short*)(ws + 1048576);
  unsigned int* counter = (unsigned int*)(ws + 1572864);
  unsigned int* list    = (unsigned int*)(ws + 1572864 + 16);

  prep_kernel<<<256, 256, 0, stream>>>(encW, decW, wEh, wEl, wDh, out, counter);
  main_kernel<<<NBLK, 512, 0, stream>>>(x, y, encb, decb, wEh, wEl, wDh,
                                        out, counter, list);
  fixup_kernel<<<256, 256, 0, stream>>>(x, y, encW, encb, decW, decb,
                                        out, counter, list);
}

// Round 4
// 105.755 us; speedup vs baseline: 1.5882x; 1.0205x over previous
//
#include <hip/hip_runtime.h>

// Problem constants (reference: B=16384, DIM_X=2048, K=128)
#define BB 16384
#define DD 2048
#define KK 128
#define NT 64            // DD / 32 k-steps
#define NCHK 16          // chunks of 4 k-steps
#define RPB 32           // rows per block
#define NBLK 512         // blocks (2 per CU)
#define DELTA 1e-3f      // argmax gap below which we re-resolve in fp64

typedef __attribute__((ext_vector_type(8))) short  bf16x8;
typedef __attribute__((ext_vector_type(4))) float  f32x4;
typedef __attribute__((ext_vector_type(4))) unsigned int u32x4;

union V16 { u32x4 u; f32x4 f; bf16x8 s; };

// Per-chunk LDS buffer: hi-plane [32 rows][128 bf16] (256 B/row) + lo-plane
// at +8192. 16B-block index XOR-swizzled with (row&7): both the staging
// ds_write_b128 pattern (4 rows x 16 blocks/wave) and the A-fragment
// ds_read_b128 pattern (16 rows x 4 blocks/wave) hit exactly 8 dwords/bank.
#define BUFB 16384       // bytes per chunk buffer (hi + lo)

// ---------------------------------------------------------------------------
// Prep: split enc_W into bf16 hi/lo and dec_W into bf16 hi, laid out in MFMA
// B-fragment order: element ((t*8+ct)*64+l)*8+j <-> W[ct*16+(l&15)][t*32+(l>>4)*8+j]
// Also zeroes the loss/accuracy accumulators and the flag counter.
// ---------------------------------------------------------------------------
__global__ __launch_bounds__(256) void prep_kernel(
    const float* __restrict__ encW, const float* __restrict__ decW,
    unsigned short* __restrict__ wEh, unsigned short* __restrict__ wEl,
    unsigned short* __restrict__ wDh,
    float* __restrict__ out, unsigned int* __restrict__ counter)
{
  int id = blockIdx.x * 256 + threadIdx.x;           // 0 .. 65535
  if (id == 0) { *counter = 0u; out[2*BB] = 0.f; out[2*BB+1] = 0.f; }
  int sel = id >> 15;                                // 0 = enc, 1 = dec
  int idx = id & 32767;
  int l  = idx & 63;
  int ct = (idx >> 6) & 7;
  int t  = idx >> 9;
  const float* W = sel ? decW : encW;
  int col = ct * 16 + (l & 15);
  int k0  = t * 32 + ((l >> 4) << 3);
  const float* src = W + (size_t)col * DD + k0;
  V16 vh, vl;
#pragma unroll
  for (int p = 0; p < 4; ++p) {
    unsigned hu[2], lu[2];
#pragma unroll
    for (int q = 0; q < 2; ++q) {
      float f = src[p*2 + q];
      unsigned u  = __float_as_uint(f);
      unsigned rh = u + 0x7FFFu + ((u >> 16) & 1u);   // RNE to bf16
      unsigned hb = rh >> 16;
      float hf = __uint_as_float(hb << 16);
      float r  = f - hf;                               // exact residual
      unsigned ur = __float_as_uint(r);
      unsigned rl = ur + 0x7FFFu + ((ur >> 16) & 1u);
      hu[q] = hb & 0xFFFFu; lu[q] = (rl >> 16) & 0xFFFFu;
    }
    vh.u[p] = (hu[1] << 16) | hu[0];
    vl.u[p] = (lu[1] << 16) | lu[0];
  }
  if (sel == 0) {
    *(u32x4*)(wEh + (size_t)idx * 8) = vh.u;
    *(u32x4*)(wEl + (size_t)idx * 8) = vl.u;
  } else {
    *(u32x4*)(wDh + (size_t)idx * 8) = vh.u;
  }
}

// ---------------------------------------------------------------------------
// Main fused kernel: 512 blocks x 512 threads (2 blocks/CU). Block = 32 rows.
// Chunked pipeline: 4 k-steps per barrier (16 barriers). x for chunk c+1 is
// loaded at the START of chunk c and ds_written at the END (latency hidden by
// the chunk's compute). B fragments global->VGPR, double-buffered at
// half-chunk (2 k-step) granularity. Per wave/k-step: 4 ds_read_b128 + 8 MFMA.
// ---------------------------------------------------------------------------
__global__ __launch_bounds__(512, 4) void main_kernel(
    const float* __restrict__ x, const float* __restrict__ y,
    const float* __restrict__ encb, const float* __restrict__ decb,
    const unsigned short* __restrict__ wEh, const unsigned short* __restrict__ wEl,
    const unsigned short* __restrict__ wDh,
    float* __restrict__ out, unsigned int* __restrict__ counter,
    unsigned int* __restrict__ list)
{
  __shared__ __align__(16) unsigned char pool[32768];
  const int tid = threadIdx.x;
  const int w = tid >> 6, l = tid & 63;
  const int rbase = blockIdx.x * RPB;

  // stage addressing: thread -> (row, 8-float segment within 128-float chunk)
  const int srow = tid >> 4, seg = tid & 15;
  const float* gXc = x + (size_t)(rbase + srow) * DD + seg * 8;
  const int woff = srow * 256 + ((seg ^ (srow & 7)) << 4);  // swizzled hi byte off

  // B fragment sources (direct to regs), col-tile = w
  const size_t boff = ((size_t)w * 64 + l) * 8;
  const unsigned short* gEh = wEh + boff;
  const unsigned short* gEl = wEl + boff;
  const unsigned short* gDh = wDh + boff;

  // A-fragment LDS byte offsets: row base + swizzled 16B-block per k-step tt
  int rowb[2], blkb[4];
#pragma unroll
  for (int rt = 0; rt < 2; ++rt) rowb[rt] = (rt * 16 + (l & 15)) * 256;
#pragma unroll
  for (int tt = 0; tt < 4; ++tt)
    blkb[tt] = (((tt * 4 + (l >> 4)) ^ (l & 7)) << 4);

  f32x4 accE[2], accD[2];
  const f32x4 zero4 = {0.f, 0.f, 0.f, 0.f};
#pragma unroll
  for (int rt = 0; rt < 2; ++rt) { accE[rt] = zero4; accD[rt] = zero4; }

  auto LDB = [&](const unsigned short* base, int t) -> bf16x8 {
    return *(const bf16x8*)(base + (size_t)t * 4096);
  };
  auto WRX = [&](int nb, f32x4 A, f32x4 Bv) {
    float fa[8] = {A[0],A[1],A[2],A[3],Bv[0],Bv[1],Bv[2],Bv[3]};
    V16 vh, vl;
#pragma unroll
    for (int p = 0; p < 4; ++p) {
      unsigned u0 = __float_as_uint(fa[2*p]);
      unsigned u1 = __float_as_uint(fa[2*p+1]);
      vh.u[p] = (u0 >> 16) | (u1 & 0xFFFF0000u);
      float r0 = fa[2*p]   - __uint_as_float(u0 & 0xFFFF0000u);
      float r1 = fa[2*p+1] - __uint_as_float(u1 & 0xFFFF0000u);
      vl.u[p] = (__float_as_uint(r0) >> 16) | (__float_as_uint(r1) & 0xFFFF0000u);
    }
    unsigned char* bp = pool + nb + woff;
    *(u32x4*)bp          = vh.u;
    *(u32x4*)(bp + 8192) = vl.u;
  };

#define LDBH(h, Eh0, El0, Dh0, Eh1, El1, Dh1) do {                  \
    int _t0 = (h) * 2;                                              \
    Eh0 = LDB(gEh, _t0);     El0 = LDB(gEl, _t0);                   \
    Dh0 = LDB(gDh, _t0);                                            \
    Eh1 = LDB(gEh, _t0 + 1); El1 = LDB(gEl, _t0 + 1);               \
    Dh1 = LDB(gDh, _t0 + 1);                                        \
  } while (0)

#define KSTEP(cbase, tt, Eh, El, Dh) do {                                        \
    _Pragma("unroll")                                                            \
    for (int rt = 0; rt < 2; ++rt) {                                             \
      const unsigned char* ap = pool + (cbase) + rowb[rt] + blkb[tt];            \
      bf16x8 ah = *(const bf16x8*)ap;                                            \
      bf16x8 al = *(const bf16x8*)(ap + 8192);                                   \
      accE[rt] = __builtin_amdgcn_mfma_f32_16x16x32_bf16(ah, Eh, accE[rt],0,0,0);\
      accE[rt] = __builtin_amdgcn_mfma_f32_16x16x32_bf16(al, Eh, accE[rt],0,0,0);\
      accE[rt] = __builtin_amdgcn_mfma_f32_16x16x32_bf16(ah, El, accE[rt],0,0,0);\
      accD[rt] = __builtin_amdgcn_mfma_f32_16x16x32_bf16(ah, Dh, accD[rt],0,0,0);\
    }                                                                            \
  } while (0)

  bf16x8 aEh0, aEl0, aDh0, aEh1, aEl1, aDh1;   // set0: even half (tt 0,1)
  bf16x8 bEh0, bEl0, bDh0, bEh1, bEl1, bDh1;   // set1: odd half  (tt 2,3)
  f32x4 xA, xB;

  // prologue: chunk 0 x -> buffer 0; B half 0 into set0
  xA = *(const f32x4*)gXc; xB = *(const f32x4*)(gXc + 4);
  LDBH(0, aEh0, aEl0, aDh0, aEh1, aEl1, aDh1);
  WRX(0, xA, xB);
  __syncthreads();

  for (int c = 0; c < NCHK; ++c) {
    const int cb = (c & 1) * BUFB;
    const int nb = cb ^ BUFB;
    // issue odd-half B (tt 2,3) and next chunk's x
    LDBH(2 * c + 1, bEh0, bEl0, bDh0, bEh1, bEl1, bDh1);
    if (c + 1 < NCHK) {
      const float* p = gXc + (c + 1) * 128;
      xA = *(const f32x4*)p; xB = *(const f32x4*)(p + 4);
    }
    __builtin_amdgcn_s_setprio(1);
    KSTEP(cb, 0, aEh0, aEl0, aDh0);
    KSTEP(cb, 1, aEh1, aEl1, aDh1);
    __builtin_amdgcn_s_setprio(0);
    // issue next chunk's even-half B into set0 (old set0 consumed above)
    if (c + 1 < NCHK)
      LDBH(2 * c + 2, aEh0, aEl0, aDh0, aEh1, aEl1, aDh1);
    __builtin_amdgcn_s_setprio(1);
    KSTEP(cb, 2, bEh0, bEl0, bDh0);
    KSTEP(cb, 3, bEh1, bEl1, bDh1);
    __builtin_amdgcn_s_setprio(0);
    if (c + 1 < NCHK) WRX(nb, xA, xB);     // x latency hidden by this chunk
    __syncthreads();
  }
#undef LDBH
#undef KSTEP

  // ---------------- epilogue (overlays the staging pool) ----------------
  float* sT  = (float*)pool;                  // [32][132] dec-GEMM results
  float* sm1 = (float*)(pool + 16896);        // [32][8] top-1
  float* sm2 = (float*)(pool + 17920);        // [32][8] top-2
  int*   si1 = (int*)  (pool + 18944);        // [32][8] argmax col

  {
    const int q = l >> 4, c = l & 15;
    const int col = w * 16 + c;
#pragma unroll
    for (int rt = 0; rt < 2; ++rt)
#pragma unroll
      for (int i = 0; i < 4; ++i)
        sT[(rt * 16 + q * 4 + i) * 132 + col] = accD[rt][i];

    const float bias = encb[col];
    float m1v[8], m2v[8]; int i1v[8];
#pragma unroll
    for (int rt = 0; rt < 2; ++rt)
#pragma unroll
      for (int i = 0; i < 4; ++i) {
        int j = rt * 4 + i;
        m1v[j] = accE[rt][i] + bias;
        m2v[j] = -3.4e38f;
        i1v[j] = col;
      }
#pragma unroll
    for (int d = 1; d < 16; d <<= 1) {
#pragma unroll
      for (int j = 0; j < 8; ++j) {
        float om1 = __shfl_xor(m1v[j], d);
        float om2 = __shfl_xor(m2v[j], d);
        int   oi  = __shfl_xor(i1v[j], d);
        if (om1 > m1v[j] || (om1 == m1v[j] && oi < i1v[j])) {
          m2v[j] = fmaxf(m1v[j], om2); m1v[j] = om1; i1v[j] = oi;
        } else {
          m2v[j] = fmaxf(m2v[j], om1);
        }
      }
    }
    if (c == 0) {
#pragma unroll
      for (int rt = 0; rt < 2; ++rt)
#pragma unroll
        for (int i = 0; i < 4; ++i) {
          int row = rt * 16 + q * 4 + i;
          int j = rt * 4 + i;
          sm1[row * 8 + w] = m1v[j];
          sm2[row * 8 + w] = m2v[j];
          si1[row * 8 + w] = i1v[j];
        }
    }
  }
  __syncthreads();

  float lossAcc = 0.f, accAcc = 0.f;
  if (tid < RPB) {
    const int row = tid, R = rbase + row;
    float m1 = -3.4e38f, m2 = -3.4e38f; int i1 = 0;
#pragma unroll
    for (int cdx = 0; cdx < 8; ++cdx) {
      float a1 = sm1[row * 8 + cdx], a2 = sm2[row * 8 + cdx];
      int ai = si1[row * 8 + cdx];
      if (a1 > m1) { m2 = fmaxf(m1, a2); m1 = a1; i1 = ai; }
      else         { m2 = fmaxf(m2, a1); }
    }
    float yh = sT[row * 132 + i1] + decb[i1];
    out[R]      = yh;
    out[BB + R] = (float)i1;
    if (m1 - m2 < DELTA) {                     // near-tie: fp64 re-resolve later
      unsigned p = atomicAdd(counter, 1u);
      list[p] = (unsigned)R;
    }
    float yv = y[R];
    float d  = yh - yv;
    lossAcc = d * d;
    float sg = (yh > 0.f) ? 1.f : ((yh < 0.f) ? -1.f : 0.f);
    accAcc = (sg == yv) ? 1.f : 0.f;
  }
#pragma unroll
  for (int d = 1; d < 64; d <<= 1) {
    lossAcc += __shfl_xor(lossAcc, d);
    accAcc  += __shfl_xor(accAcc, d);
  }
  if (tid == 0) {
    atomicAdd(&out[2*BB],     lossAcc * (1.f / BB));
    atomicAdd(&out[2*BB + 1], accAcc  * (1.f / BB));
  }
}

// ---------------------------------------------------------------------------
// Fixup: fp64 re-resolution of flagged near-tie rows; patches y_hat, z_hat,
// and the loss/accuracy atomics.
// ---------------------------------------------------------------------------
__global__ __launch_bounds__(256) void fixup_kernel(
    const float* __restrict__ x, const float* __restrict__ y,
    const float* __restrict__ encW, const float* __restrict__ encb,
    const float* __restrict__ decW, const float* __restrict__ decb,
    float* __restrict__ out,
    const unsigned int* __restrict__ counter, const unsigned int* __restrict__ list)
{
  __shared__ double sp[256];
  __shared__ double sc[128];
  __shared__ int ksh;
  const int n = (int)*counter;
  const int tid = threadIdx.x;
  for (int e = blockIdx.x; e < n; e += gridDim.x) {
    const int R = (int)list[e];
    const float* xr = x + (size_t)R * DD;
    {
      const int col = tid & 127, seg = tid >> 7;
      const float* wrow = encW + (size_t)col * DD + seg * 1024;
      const float* xs = xr + seg * 1024;
      double s = 0.0;
      for (int k = 0; k < 1024; ++k) s = fma((double)xs[k], (double)wrow[k], s);
      sp[tid] = s;
    }
    __syncthreads();
    if (tid < 128) sc[tid] = sp[tid] + sp[tid + 128] + (double)encb[tid];
    __syncthreads();
    if (tid == 0) {
      double best = sc[0]; int bi = 0;
      for (int c = 1; c < 128; ++c) if (sc[c] > best) { best = sc[c]; bi = c; }
      ksh = bi;
    }
    __syncthreads();
    const int kstar = ksh;
    {
      const float* dr = decW + (size_t)kstar * DD;
      const int k0 = tid * 8;
      double s = 0.0;
#pragma unroll
      for (int j = 0; j < 8; ++j) s = fma((double)xr[k0 + j], (double)dr[k0 + j], s);
      sp[tid] = s;
    }
    __syncthreads();
    for (int st = 128; st > 0; st >>= 1) {
      if (tid < st) sp[tid] += sp[tid + st];
      __syncthreads();
    }
    if (tid == 0) {
      float yh = (float)(sp[0] + (double)decb[kstar]);
      float yv = y[R];
      float old = out[R];
      float dn = yh - yv, dol = old - yv;
      atomicAdd(&out[2*BB], (dn*dn - dol*dol) * (1.f / BB));
      float sgn = (yh  > 0.f) ? 1.f : ((yh  < 0.f) ? -1.f : 0.f);
      float sgo = (old > 0.f) ? 1.f : ((old < 0.f) ? -1.f : 0.f);
      float mn = (sgn == yv) ? 1.f : 0.f;
      float mo = (sgo == yv) ? 1.f : 0.f;
      atomicAdd(&out[2*BB + 1], (mn - mo) * (1.f / BB));
      out[R]      = yh;
      out[BB + R] = (float)kstar;
    }
    __syncthreads();
  }
}

extern "C" void kernel_launch(void* const* d_in, const int* in_sizes, int n_in,
                              void* d_out, int out_size, void* d_ws, size_t ws_size,
                              hipStream_t stream)
{
  const float* x    = (const float*)d_in[0];
  const float* y    = (const float*)d_in[1];
  // d_in[2] = z (unused by the reference computation)
  const float* encW = (const float*)d_in[3];
  const float* encb = (const float*)d_in[4];
  const float* decW = (const float*)d_in[5];   // [1,128,2048] -> row-major [128][2048]
  const float* decb = (const float*)d_in[6];
  float* out = (float*)d_out;

  unsigned char* ws = (unsigned char*)d_ws;
  unsigned short* wEh = (unsigned short*)ws;
  unsigned short* wEl = (unsigned short*)(ws + 524288);
  unsigned short* wDh = (unsigned short*)(ws + 1048576);
  unsigned int* counter = (unsigned int*)(ws + 1572864);
  unsigned int* list    = (unsigned int*)(ws + 1572864 + 16);

  prep_kernel<<<256, 256, 0, stream>>>(encW, decW, wEh, wEl, wDh, out, counter);
  main_kernel<<<NBLK, 512, 0, stream>>>(x, y, encb, decb, wEh, wEl, wDh,
                                        out, counter, list);
  fixup_kernel<<<256, 256, 0, stream>>>(x, y, encW, encb, decW, decb,
                                        out, counter, list);
}